// Round 1
// baseline (99.724 us; speedup 1.0000x reference)
//
#include <hip/hip_runtime.h>
#include <hip/hip_bf16.h>

typedef __bf16 bf16x8 __attribute__((ext_vector_type(8)));
typedef float  f32x4  __attribute__((ext_vector_type(4)));

#define NCLQ   500000
#define NF     64
#define HID    128
#define NTILES 62500   // 1,000,000 edges / 16 per wave-tile
#define RTILES 31250   // tiles belonging to cliques_r (500000/16)

__device__ inline bf16x8 mul_cvt(float4 xa, float4 xb, float4 ya, float4 yb) {
    bf16x8 r;
    r[0] = (__bf16)(xa.x * ya.x); r[1] = (__bf16)(xa.y * ya.y);
    r[2] = (__bf16)(xa.z * ya.z); r[3] = (__bf16)(xa.w * ya.w);
    r[4] = (__bf16)(xb.x * yb.x); r[5] = (__bf16)(xb.y * yb.y);
    r[6] = (__bf16)(xb.z * yb.z); r[7] = (__bf16)(xb.w * yb.w);
    return r;
}

__global__ __launch_bounds__(256) void edge_pred_kernel(
    const float* __restrict__ nf,
    const int*   __restrict__ cr,
    const int*   __restrict__ cs,
    const float* __restrict__ w5,
    const float* __restrict__ b5,
    const float* __restrict__ w6,
    const float* __restrict__ b6,
    float*       __restrict__ out)
{
    const int lane = threadIdx.x & 63;
    const int wid  = threadIdx.x >> 6;
    const int i    = lane & 15;   // edge-in-tile (A row / C col-index role per layout)
    const int g    = lane >> 4;   // lane group 0..3

    // ---- one-time per-wave preload: W5 fragments (bf16), b5, w6diff ----
    // B fragment for N-tile t, K-block kb: elem e holds W5[32*kb + 8*g + e][16*t + i].
    // The assumed k-map (8*g+e) is a bijection over k in [0,32); since A uses the
    // SAME assumed map, the MFMA contraction is correct for any true HW k-layout.
    bf16x8 bfrag[8][2];
    float  b5r[8], wdr[8];
#pragma unroll
    for (int t = 0; t < 8; ++t) {
        const int col = 16 * t + i;
        b5r[t] = b5[col];
        wdr[t] = w6[2 * col] - w6[2 * col + 1];   // W6[:,0]-W6[:,1]
#pragma unroll
        for (int kb = 0; kb < 2; ++kb) {
            bf16x8 f;
#pragma unroll
            for (int e = 0; e < 8; ++e) {
                const int k = 32 * kb + 8 * g + e;
                f[e] = (__bf16)w5[k * HID + col];
            }
            bfrag[t][kb] = f;
        }
    }
    const float bdiff = b6[0] - b6[1];

    const int gw = blockIdx.x * 4 + wid;
    const int nw = gridDim.x * 4;

    for (int tile = gw; tile < NTILES; tile += nw) {
        // tiles never straddle the r/s boundary (500000 % 16 == 0)
        const bool  is_r = (tile < RTILES);
        const int*  cl   = is_r ? cr : cs;
        const long  ce   = (long)(is_r ? tile : tile - RTILES) * 16 + i;

        const int2 idx = *(const int2*)(cl + ce * 4);   // cols 0,1 of this clique
        const float* p0 = nf + (long)idx.x * NF;
        const float* p1 = nf + (long)idx.y * NF;

        // gather 2x (k in [8g,8g+8) and [32+8g,32+8g+8)) from both nodes
        const float4 xa = *(const float4*)(p0 + 8 * g);
        const float4 xb = *(const float4*)(p0 + 8 * g + 4);
        const float4 ya = *(const float4*)(p1 + 8 * g);
        const float4 yb = *(const float4*)(p1 + 8 * g + 4);
        const float4 xc = *(const float4*)(p0 + 32 + 8 * g);
        const float4 xd = *(const float4*)(p0 + 32 + 8 * g + 4);
        const float4 yc = *(const float4*)(p1 + 32 + 8 * g);
        const float4 yd = *(const float4*)(p1 + 32 + 8 * g + 4);

        const bf16x8 a0 = mul_cvt(xa, xb, ya, yb);   // k in [0,32)
        const bf16x8 a1 = mul_cvt(xc, xd, yc, yd);   // k in [32,64)

        // ---- GEMM-1: h(16 edges x 128) via 8 N-tiles x 2 K-blocks ----
        f32x4 acc[8];
#pragma unroll
        for (int t = 0; t < 8; ++t) {
            f32x4 z = {0.f, 0.f, 0.f, 0.f};
            z = __builtin_amdgcn_mfma_f32_16x16x32_bf16(a0, bfrag[t][0], z, 0, 0, 0);
            z = __builtin_amdgcn_mfma_f32_16x16x32_bf16(a1, bfrag[t][1], z, 0, 0, 0);
            acc[t] = z;
        }

        // ---- epilogue: relu(+b5), dot with w6diff, reduce over cols ----
        // C layout: col = 16t + (lane&15), row(edge) = 4*g + r   [m89-verified]
        float s0, s1, s2, s3;
#pragma unroll
        for (int r = 0; r < 4; ++r) {
            float a = 0.f;
#pragma unroll
            for (int t = 0; t < 8; ++t) {
                float h = acc[t][r] + b5r[t];
                h = fmaxf(h, 0.f);
                a = fmaf(h, wdr[t], a);
            }
            // sum across the 16 lanes of this group (same g => same rows)
            a += __shfl_xor(a, 1);
            a += __shfl_xor(a, 2);
            a += __shfl_xor(a, 4);
            a += __shfl_xor(a, 8);
            if (r == 0) s0 = a; else if (r == 1) s1 = a; else if (r == 2) s2 = a; else s3 = a;
        }

        // ---- softmax(2) == sigmoid(logit0-logit1); write 8 floats per group ----
        if (i < 8) {
            const int r = i >> 1, c = i & 1;
            const float sv = (r == 0) ? s0 : (r == 1) ? s1 : (r == 2) ? s2 : s3;
            const float z  = sv + bdiff;
            const float pz = 1.0f / (1.0f + __expf(-z));
            const float v  = c ? (1.0f - pz) : pz;
            // out index: 2*edge + c = tile*32 + 8*g + i  (contiguous per group)
            out[(long)tile * 32 + 8 * g + i] = v;
        }
    }
}

extern "C" void kernel_launch(void* const* d_in, const int* in_sizes, int n_in,
                              void* d_out, int out_size, void* d_ws, size_t ws_size,
                              hipStream_t stream) {
    const float* nf = (const float*)d_in[3];   // node_features (x = d_in[0] is unused by reference)
    const int*   cr = (const int*)d_in[1];
    const int*   cs = (const int*)d_in[2];
    const float* w5 = (const float*)d_in[4];
    const float* b5 = (const float*)d_in[5];
    const float* w6 = (const float*)d_in[6];
    const float* b6 = (const float*)d_in[7];
    float* out = (float*)d_out;

    // 768 blocks x 4 waves = 3072 waves, ~20 tiles each (grid-stride);
    // keeps per-wave W5-fragment preload amortized.
    hipLaunchKernelGGL(edge_pred_kernel, dim3(768), dim3(256), 0, stream,
                       nf, cr, cs, w5, b5, w6, b6, out);
}

// Round 2
// 62.552 us; speedup vs baseline: 1.5943x; 1.5943x over previous
//
#include <hip/hip_runtime.h>
#include <hip/hip_bf16.h>
#include <hip/hip_fp16.h>

typedef _Float16 half8 __attribute__((ext_vector_type(8)));
typedef float    f32x4 __attribute__((ext_vector_type(4)));

#define NCLQ      500000
#define NF        64
#define HID       128
#define NTILES    62500   // 1,000,000 edges / 16 per wave-tile
#define RTILES    31250   // tiles belonging to cliques_r
#define NFH_ELEMS 6400000 // 100000 * 64

// ---- pre-pass: f32 -> fp16 for node_features and W5 (into d_ws) ----
__global__ __launch_bounds__(256) void cvt_kernel(const float* __restrict__ nf,
                                                  const float* __restrict__ w5,
                                                  _Float16* __restrict__ nfh,
                                                  _Float16* __restrict__ w5h)
{
    const long id = (long)blockIdx.x * blockDim.x + threadIdx.x; // 8 elems each
    const long NCHUNK = NFH_ELEMS / 8;      // 800000
    const long WCHUNK = (NF * HID) / 8;     // 1024
    const float* src; _Float16* dst; long c;
    if (id < NCHUNK)                { src = nf; dst = nfh; c = id; }
    else if (id < NCHUNK + WCHUNK)  { src = w5; dst = w5h; c = id - NCHUNK; }
    else return;
    const float4 u = ((const float4*)src)[c * 2 + 0];
    const float4 v = ((const float4*)src)[c * 2 + 1];
    half8 h;
    h[0] = (_Float16)u.x; h[1] = (_Float16)u.y; h[2] = (_Float16)u.z; h[3] = (_Float16)u.w;
    h[4] = (_Float16)v.x; h[5] = (_Float16)v.y; h[6] = (_Float16)v.z; h[7] = (_Float16)v.w;
    ((half8*)dst)[c] = h;
}

// ---- main kernel: 16 edges per wave-tile, 2-deep software pipeline ----
template <int PRE>
__global__ __launch_bounds__(256, 4) void edge_pred_kernel(
    const float*    __restrict__ nf,
    const _Float16* __restrict__ nfh,
    const int*      __restrict__ cr,
    const int*      __restrict__ cs,
    const float*    __restrict__ w5,
    const _Float16* __restrict__ w5h,
    const float*    __restrict__ b5,
    const float*    __restrict__ w6,
    const float*    __restrict__ b6,
    float*          __restrict__ out)
{
    const int lane = threadIdx.x & 63;
    const int wid  = threadIdx.x >> 6;
    const int i    = lane & 15;   // edge-in-tile
    const int g    = lane >> 4;   // lane group 0..3

    // ---- per-wave preload: W5 fragments (fp16), b5, w6[:,0]-w6[:,1] ----
    // B fragment elem e of (t,kb) holds W5[32*kb + 8*g + e][16*t + i]; A uses the
    // same assumed k-map so the contraction is layout-safe.
    half8 bfrag[8][2];
    float b5r[8], wdr[8];
#pragma unroll
    for (int t = 0; t < 8; ++t) {
        const int col = 16 * t + i;
        b5r[t] = b5[col];
        wdr[t] = w6[2 * col] - w6[2 * col + 1];
#pragma unroll
        for (int kb = 0; kb < 2; ++kb) {
            half8 f;
#pragma unroll
            for (int e = 0; e < 8; ++e) {
                const int k = 32 * kb + 8 * g + e;
                f[e] = PRE ? w5h[k * HID + col] : (_Float16)w5[k * HID + col];
            }
            bfrag[t][kb] = f;
        }
    }
    const float bdiff = b6[0] - b6[1];

    const int gw = blockIdx.x * 4 + wid;
    const int nw = gridDim.x * 4;
    if (gw >= NTILES) return;

    auto clq = [&](int T) -> int2 {
        T = (T < NTILES) ? T : (NTILES - 1);          // clamp for prefetch tail
        const bool is_r = (T < RTILES);
        const int* cl   = is_r ? cr : cs;
        const long e    = (long)(is_r ? T : T - RTILES) * 16 + i;
        return *(const int2*)(cl + e * 4);            // cols 0,1 of the clique
    };
    auto gather = [&](int2 idx, half8& d0a, half8& d0b, half8& d1a, half8& d1b) {
        if constexpr (PRE) {
            const _Float16* p0 = nfh + (long)idx.x * NF;
            const _Float16* p1 = nfh + (long)idx.y * NF;
            d0a = *(const half8*)(p0 + 8 * g);
            d0b = *(const half8*)(p0 + 32 + 8 * g);
            d1a = *(const half8*)(p1 + 8 * g);
            d1b = *(const half8*)(p1 + 32 + 8 * g);
        } else {
            const float* p0 = nf + (long)idx.x * NF;
            const float* p1 = nf + (long)idx.y * NF;
            const float4 xa = *(const float4*)(p0 + 8 * g);
            const float4 xb = *(const float4*)(p0 + 8 * g + 4);
            const float4 ya = *(const float4*)(p1 + 8 * g);
            const float4 yb = *(const float4*)(p1 + 8 * g + 4);
            const float4 xc = *(const float4*)(p0 + 32 + 8 * g);
            const float4 xd = *(const float4*)(p0 + 32 + 8 * g + 4);
            const float4 yc = *(const float4*)(p1 + 32 + 8 * g);
            const float4 yd = *(const float4*)(p1 + 32 + 8 * g + 4);
            d0a[0]=(_Float16)xa.x; d0a[1]=(_Float16)xa.y; d0a[2]=(_Float16)xa.z; d0a[3]=(_Float16)xa.w;
            d0a[4]=(_Float16)xb.x; d0a[5]=(_Float16)xb.y; d0a[6]=(_Float16)xb.z; d0a[7]=(_Float16)xb.w;
            d0b[0]=(_Float16)xc.x; d0b[1]=(_Float16)xc.y; d0b[2]=(_Float16)xc.z; d0b[3]=(_Float16)xc.w;
            d0b[4]=(_Float16)xd.x; d0b[5]=(_Float16)xd.y; d0b[6]=(_Float16)xd.z; d0b[7]=(_Float16)xd.w;
            d1a[0]=(_Float16)ya.x; d1a[1]=(_Float16)ya.y; d1a[2]=(_Float16)ya.z; d1a[3]=(_Float16)ya.w;
            d1a[4]=(_Float16)yb.x; d1a[5]=(_Float16)yb.y; d1a[6]=(_Float16)yb.z; d1a[7]=(_Float16)yb.w;
            d1b[0]=(_Float16)yc.x; d1b[1]=(_Float16)yc.y; d1b[2]=(_Float16)yc.z; d1b[3]=(_Float16)yc.w;
            d1b[4]=(_Float16)yd.x; d1b[5]=(_Float16)yd.y; d1b[6]=(_Float16)yd.z; d1b[7]=(_Float16)yd.w;
        }
    };

    // ---- software pipeline: idx for t+2, data for t+1, compute t ----
    int2 idxA = clq(gw);
    half8 d0a, d0b, d1a, d1b;
    gather(idxA, d0a, d0b, d1a, d1b);
    int2 idxB = clq(gw + nw);

    for (int tile = gw; tile < NTILES; tile += nw) {
        const int2 idxC = clq(tile + 2 * nw);          // idx prefetch (t+2)
        half8 e0a, e0b, e1a, e1b;
        gather(idxB, e0a, e0b, e1a, e1b);              // data prefetch (t+1)

        // compute current tile
        const half8 a0 = d0a * d1a;                    // k in [0,32)  (v_pk_mul_f16)
        const half8 a1 = d0b * d1b;                    // k in [32,64)

        f32x4 acc[8];
#pragma unroll
        for (int t = 0; t < 8; ++t) {
            f32x4 z = {0.f, 0.f, 0.f, 0.f};
            z = __builtin_amdgcn_mfma_f32_16x16x32_f16(a0, bfrag[t][0], z, 0, 0, 0);
            z = __builtin_amdgcn_mfma_f32_16x16x32_f16(a1, bfrag[t][1], z, 0, 0, 0);
            acc[t] = z;
        }

        // epilogue: relu(+b5), dot with w6diff, 16-lane reduce per row
        float s0, s1, s2, s3;
#pragma unroll
        for (int r = 0; r < 4; ++r) {
            float a = 0.f;
#pragma unroll
            for (int t = 0; t < 8; ++t) {
                float h = acc[t][r] + b5r[t];
                h = fmaxf(h, 0.f);
                a = fmaf(h, wdr[t], a);
            }
            a += __shfl_xor(a, 1);
            a += __shfl_xor(a, 2);
            a += __shfl_xor(a, 4);
            a += __shfl_xor(a, 8);
            if (r == 0) s0 = a; else if (r == 1) s1 = a; else if (r == 2) s2 = a; else s3 = a;
        }

        if (i < 8) {
            const int r = i >> 1, c = i & 1;
            const float sv = (r == 0) ? s0 : (r == 1) ? s1 : (r == 2) ? s2 : s3;
            const float z  = sv + bdiff;
            const float pz = 1.0f / (1.0f + __expf(-z));
            out[(long)tile * 32 + 8 * g + i] = c ? (1.0f - pz) : pz;
        }

        // rotate pipeline registers
        d0a = e0a; d0b = e0b; d1a = e1a; d1b = e1b;
        idxB = idxC;
    }
}

extern "C" void kernel_launch(void* const* d_in, const int* in_sizes, int n_in,
                              void* d_out, int out_size, void* d_ws, size_t ws_size,
                              hipStream_t stream) {
    const float* nf = (const float*)d_in[3];
    const int*   cr = (const int*)d_in[1];
    const int*   cs = (const int*)d_in[2];
    const float* w5 = (const float*)d_in[4];
    const float* b5 = (const float*)d_in[5];
    const float* w6 = (const float*)d_in[6];
    const float* b6 = (const float*)d_in[7];
    float* out = (float*)d_out;

    const size_t need = (size_t)NFH_ELEMS * 2 + (size_t)NF * HID * 2;
    if (ws_size >= need) {
        _Float16* nfh = (_Float16*)d_ws;
        _Float16* w5h = (_Float16*)((char*)d_ws + (size_t)NFH_ELEMS * 2);
        const int cvt_blocks = (NFH_ELEMS / 8 + NF * HID / 8 + 255) / 256; // 3130
        hipLaunchKernelGGL(cvt_kernel, dim3(cvt_blocks), dim3(256), 0, stream,
                           nf, w5, nfh, w5h);
        hipLaunchKernelGGL((edge_pred_kernel<1>), dim3(1024), dim3(256), 0, stream,
                           nf, nfh, cr, cs, w5, w5h, b5, w6, b6, out);
    } else {
        hipLaunchKernelGGL((edge_pred_kernel<0>), dim3(1024), dim3(256), 0, stream,
                           nf, (const _Float16*)nullptr, cr, cs, w5,
                           (const _Float16*)nullptr, b5, w6, b6, out);
    }
}